// Round 7
// baseline (331.452 us; speedup 1.0000x reference)
//
#include <hip/hip_runtime.h>

#define N_NODES 16384
#define N_EDGES 262144
#define D 256
#define B_GRAPHS 32
#define NODES_PER_GRAPH 512   // N_NODES / B_GRAPHS
#define MAXDEG 64             // Poisson(16): P(deg>64) ~ 1e-17
#define L2CAP 2080            // max captured l2 nodes: 32 roots + 32*64 bucket slots
#define TAILB 128             // tail grid (must divide barrier math)

typedef unsigned short u16;
typedef __attribute__((ext_vector_type(8)))  short bf16x8;
typedef __attribute__((ext_vector_type(16))) float f32x16;
typedef __attribute__((ext_vector_type(8)))  unsigned short u16x8;
typedef __attribute__((ext_vector_type(4)))  unsigned short u16x4;

static __device__ __forceinline__ u16 f2bf(float f) {
    unsigned int u = __float_as_uint(f);
    unsigned int r = (u + 0x7FFFu + ((u >> 16) & 1u)) >> 16;   // RNE
    return (u16)r;
}
static __device__ __forceinline__ float bf2f(u16 h) {
    return __uint_as_float(((unsigned int)h) << 16);
}
// involution swizzle on byte offsets within an 8KB [128 rows x 64B] LDS array
static __device__ __forceinline__ int swz(int a) {
    return a ^ (((a >> 7) & 3) << 4);
}
static __device__ __forceinline__ void gload16(const void* g, void* l) {
    __builtin_amdgcn_global_load_lds(
        (const __attribute__((address_space(1))) unsigned int*)g,
        (__attribute__((address_space(3))) unsigned int*)l, 16, 0, 0);
}

// ---------------------------------------------------------------------------
// prep: [0,2048) split x; [2048,2144) W transpose+split; [2144,2208) zero cnt;
//       [2208,2272) init flags (roots pre-set); [2272] seed l2 list
// ---------------------------------------------------------------------------
__global__ __launch_bounds__(256) void prep_kernel(
    const float* __restrict__ x, const float* __restrict__ Wl,
    const float* __restrict__ Wr,
    u16* __restrict__ Xhi, u16* __restrict__ Xlo,
    u16* __restrict__ WtL_hi, u16* __restrict__ WtL_lo,
    u16* __restrict__ WtR_hi, u16* __restrict__ WtR_lo,
    int* __restrict__ cnt, int* __restrict__ flags,
    int* __restrict__ l2list, int* __restrict__ l2cnt)
{
    __shared__ float S[64][68];
    const int bid = blockIdx.x;
    const int t = threadIdx.x;
    if (bid < 2048) {
        size_t e0 = ((size_t)bid * 256 + t) * 8;
        float4 v0 = *(const float4*)&x[e0];
        float4 v1 = *(const float4*)&x[e0 + 4];
        float xs[8] = {v0.x, v0.y, v0.z, v0.w, v1.x, v1.y, v1.z, v1.w};
        u16x8 H, L;
        #pragma unroll
        for (int j = 0; j < 8; ++j) {
            u16 h = f2bf(xs[j]);
            H[j] = h; L[j] = f2bf(xs[j] - bf2f(h));
        }
        *(u16x8*)&Xhi[e0] = H;
        *(u16x8*)&Xlo[e0] = L;
    } else if (bid < 2144) {
        int mb = bid - 2048;
        int mat = mb / 16, sub = mb % 16;
        int kt = (sub >> 2) * 64, nt = (sub & 3) * 64;
        const float* src = (mat < 3) ? Wl + (size_t)mat * 65536 : Wr + (size_t)(mat - 3) * 65536;
        u16* dhi = (mat < 3) ? WtL_hi + (size_t)mat * 65536 : WtR_hi + (size_t)(mat - 3) * 65536;
        u16* dlo = (mat < 3) ? WtL_lo + (size_t)mat * 65536 : WtR_lo + (size_t)(mat - 3) * 65536;
        int r = t >> 2, c0 = (t & 3) * 16;
        #pragma unroll
        for (int j = 0; j < 4; ++j) {
            float4 v = *(const float4*)&src[(size_t)(kt + r) * 256 + nt + c0 + j * 4];
            *(float4*)&S[r][c0 + j * 4] = v;
        }
        __syncthreads();
        int n = t >> 2, kc = (t & 3) * 16;
        u16x8 h0, h1, l0, l1;
        #pragma unroll
        for (int j = 0; j < 8; ++j) {
            float xv = S[kc + j][n];
            u16 h = f2bf(xv);
            h0[j] = h; l0[j] = f2bf(xv - bf2f(h));
            float y = S[kc + 8 + j][n];
            u16 g = f2bf(y);
            h1[j] = g; l1[j] = f2bf(y - bf2f(g));
        }
        size_t o = (size_t)(nt + n) * 256 + kt + kc;
        *(u16x8*)&dhi[o] = h0; *(u16x8*)&dhi[o + 8] = h1;
        *(u16x8*)&dlo[o] = l0; *(u16x8*)&dlo[o + 8] = l1;
    } else if (bid < 2208) {
        cnt[(bid - 2144) * 256 + t] = 0;
    } else if (bid < 2272) {
        int i = (bid - 2208) * 256 + t;
        flags[i] = ((i & (NODES_PER_GRAPH - 1)) == 0) ? 1 : 0;  // roots pre-marked
    } else {
        if (t < B_GRAPHS) l2list[t] = t * NODES_PER_GRAPH;
        if (t == 0) *l2cnt = B_GRAPHS;
    }
}

// ---------------------------------------------------------------------------
// bucket fill + L2-active capture (srcs of edges into roots, deduped)
// ---------------------------------------------------------------------------
__global__ __launch_bounds__(256) void fill_bucket_kernel(const int* __restrict__ edge,
                                                          int* __restrict__ cnt,
                                                          int* __restrict__ col,
                                                          int* __restrict__ flags,
                                                          int* __restrict__ l2list,
                                                          int* __restrict__ l2cnt) {
    int e = blockIdx.x * 256 + threadIdx.x;
    int dst = edge[N_EDGES + e];
    int src = edge[e];
    int slot = atomicAdd(&cnt[dst], 1);
    if (slot < MAXDEG) {
        col[dst * MAXDEG + slot] = src;
        if ((dst & (NODES_PER_GRAPH - 1)) == 0) {     // dst is a root
            if (atomicCAS(&flags[src], 0, 1) == 0) {
                int p = atomicAdd(l2cnt, 1);
                if (p < L2CAP) l2list[p] = src;
            }
        }
    }
}

// ---------------------------------------------------------------------------
// per-node mean-aggregate helper (64-lane wave), gathers HI only, writes hi/lo
// ---------------------------------------------------------------------------
static __device__ __forceinline__ void agg_node(const u16* __restrict__ Xs,
                                                const int* __restrict__ cnt,
                                                const int* __restrict__ col,
                                                int node, int destrow, int lane,
                                                u16* __restrict__ Ah,
                                                u16* __restrict__ Al) {
    int c = cnt[node];
    if (c > MAXDEG) c = MAXDEG;
    int my = (lane < c) ? col[node * MAXDEG + lane] : 0;
    float a0 = 0.f, a1 = 0.f, a2 = 0.f, a3 = 0.f;
    int j = 0;
    for (; j + 8 <= c; j += 8) {
        u16x4 v[8];
        #pragma unroll
        for (int q = 0; q < 8; ++q) {
            int s = __shfl(my, j + q);
            v[q] = *(const u16x4*)&Xs[(size_t)s * D + lane * 4];
        }
        #pragma unroll
        for (int q = 0; q < 8; ++q) {
            a0 += bf2f(v[q][0]); a1 += bf2f(v[q][1]);
            a2 += bf2f(v[q][2]); a3 += bf2f(v[q][3]);
        }
    }
    for (; j < c; ++j) {
        int s = __shfl(my, j);
        u16x4 v = *(const u16x4*)&Xs[(size_t)s * D + lane * 4];
        a0 += bf2f(v[0]); a1 += bf2f(v[1]); a2 += bf2f(v[2]); a3 += bf2f(v[3]);
    }
    float id = 1.0f / (float)(c < 1 ? 1 : c);
    float m[4] = {a0 * id, a1 * id, a2 * id, a3 * id};
    u16x4 H, L;
    #pragma unroll
    for (int q = 0; q < 4; ++q) {
        u16 h = f2bf(m[q]);
        H[q] = h; L[q] = f2bf(m[q] - bf2f(h));
    }
    *(u16x4*)&Ah[(size_t)destrow * D + lane * 4] = H;
    *(u16x4*)&Al[(size_t)destrow * D + lane * 4] = L;
}

// ---------------------------------------------------------------------------
// full-graph aggregation (layer 1 only)
// ---------------------------------------------------------------------------
__global__ __launch_bounds__(256) void agg_kernel(const u16* __restrict__ Xhi,
                                                  const int* __restrict__ cnt,
                                                  const int* __restrict__ col,
                                                  u16* __restrict__ Agghi,
                                                  u16* __restrict__ Agglo) {
    int node = blockIdx.x * 4 + (threadIdx.x >> 6);
    agg_node(Xhi, cnt, col, node, node, threadIdx.x & 63, Agghi, Agglo);
}

// ---------------------------------------------------------------------------
// full MFMA dual GEMM (layer 1 only) — R4/R6 proven code
// ---------------------------------------------------------------------------
__global__ __launch_bounds__(256) void gemm_mfma_kernel(
    const u16* __restrict__ Xhi,   const u16* __restrict__ Xlo,
    const u16* __restrict__ Agghi, const u16* __restrict__ Agglo,
    const u16* __restrict__ WtRhi, const u16* __restrict__ WtRlo,
    const u16* __restrict__ WtLhi, const u16* __restrict__ WtLlo,
    const float* __restrict__ bias,
    u16* __restrict__ Xohi, u16* __restrict__ Xolo)
{
    __shared__ u16 lds[2][4][4096];   // [buf][Ahi,Alo,Bhi,Blo][8KB]

    const int tid  = threadIdx.x;
    const int w    = tid >> 6, lane = tid & 63;
    const int wm   = w >> 1, wn = w & 1;
    const int bid  = blockIdx.x;
    const int m0   = (bid >> 1) * 128;
    const int n0   = (bid & 1) * 128;

    f32x16 acc[4];
    #pragma unroll
    for (int f = 0; f < 4; ++f)
        #pragma unroll
        for (int j = 0; j < 16; ++j) acc[f][j] = 0.f;

    const int r32 = lane & 31;
    const int khb = (lane >> 5) * 16;

    auto stage = [&](int buf, int tt) {
        const u16* src; int rbase;
        const int k0 = (tt & 7) * 32;
        const bool ph2 = tt >= 8;
        if      (w == 0) { src = ph2 ? Agghi : Xhi;  rbase = m0; }
        else if (w == 1) { src = ph2 ? Agglo : Xlo;  rbase = m0; }
        else if (w == 2) { src = ph2 ? WtLhi : WtRhi; rbase = n0; }
        else             { src = ph2 ? WtLlo : WtRlo; rbase = n0; }
        char* base = (char*)&lds[buf][w][0];
        #pragma unroll
        for (int i = 0; i < 8; ++i) {
            int o = i * 1024 + lane * 16;
            int a = swz(o);
            const u16* g = src + (size_t)(rbase + (a >> 6)) * D + k0 + ((a & 63) >> 1);
            gload16(g, base + i * 1024);
        }
    };

    auto compute = [&](int buf) {
        const char* Ah = (const char*)&lds[buf][0][0];
        const char* Al = (const char*)&lds[buf][1][0];
        const char* Bh = (const char*)&lds[buf][2][0];
        const char* Bl = (const char*)&lds[buf][3][0];
        #pragma unroll
        for (int s = 0; s < 2; ++s) {
            const int cb = s * 32 + khb;
            const int ra0 = wm * 64 + r32, ra1 = ra0 + 32;
            const int rb0 = wn * 64 + r32, rb1 = rb0 + 32;
            bf16x8 ah0 = *(const bf16x8*)(Ah + swz(ra0 * 64 + cb));
            bf16x8 ah1 = *(const bf16x8*)(Ah + swz(ra1 * 64 + cb));
            bf16x8 al0 = *(const bf16x8*)(Al + swz(ra0 * 64 + cb));
            bf16x8 al1 = *(const bf16x8*)(Al + swz(ra1 * 64 + cb));
            bf16x8 bh0 = *(const bf16x8*)(Bh + swz(rb0 * 64 + cb));
            bf16x8 bh1 = *(const bf16x8*)(Bh + swz(rb1 * 64 + cb));
            bf16x8 bl0 = *(const bf16x8*)(Bl + swz(rb0 * 64 + cb));
            bf16x8 bl1 = *(const bf16x8*)(Bl + swz(rb1 * 64 + cb));
            acc[0] = __builtin_amdgcn_mfma_f32_32x32x16_bf16(ah0, bh0, acc[0], 0, 0, 0);
            acc[1] = __builtin_amdgcn_mfma_f32_32x32x16_bf16(ah0, bh1, acc[1], 0, 0, 0);
            acc[2] = __builtin_amdgcn_mfma_f32_32x32x16_bf16(ah1, bh0, acc[2], 0, 0, 0);
            acc[3] = __builtin_amdgcn_mfma_f32_32x32x16_bf16(ah1, bh1, acc[3], 0, 0, 0);
            acc[0] = __builtin_amdgcn_mfma_f32_32x32x16_bf16(al0, bh0, acc[0], 0, 0, 0);
            acc[1] = __builtin_amdgcn_mfma_f32_32x32x16_bf16(al0, bh1, acc[1], 0, 0, 0);
            acc[2] = __builtin_amdgcn_mfma_f32_32x32x16_bf16(al1, bh0, acc[2], 0, 0, 0);
            acc[3] = __builtin_amdgcn_mfma_f32_32x32x16_bf16(al1, bh1, acc[3], 0, 0, 0);
            acc[0] = __builtin_amdgcn_mfma_f32_32x32x16_bf16(ah0, bl0, acc[0], 0, 0, 0);
            acc[1] = __builtin_amdgcn_mfma_f32_32x32x16_bf16(ah0, bl1, acc[1], 0, 0, 0);
            acc[2] = __builtin_amdgcn_mfma_f32_32x32x16_bf16(ah1, bl0, acc[2], 0, 0, 0);
            acc[3] = __builtin_amdgcn_mfma_f32_32x32x16_bf16(ah1, bl1, acc[3], 0, 0, 0);
        }
    };

    stage(0, 0);
    __syncthreads();
    int cur = 0;
    for (int t = 0; t < 16; ++t) {
        if (t < 15) stage(cur ^ 1, t + 1);
        compute(cur);
        __syncthreads();
        cur ^= 1;
    }

    #pragma unroll
    for (int fm = 0; fm < 2; ++fm) {
        #pragma unroll
        for (int fn = 0; fn < 2; ++fn) {
            const int colc = n0 + wn * 64 + fn * 32 + r32;
            const int rowb = m0 + wm * 64 + fm * 32 + 4 * (lane >> 5);
            const float bv = bias[colc];
            #pragma unroll
            for (int reg = 0; reg < 16; ++reg) {
                const int row = rowb + (reg & 3) + 8 * (reg >> 2);
                float v = acc[fm * 2 + fn][reg] + bv;
                u16 h = f2bf(v);
                Xohi[(size_t)row * D + colc] = h;
                Xolo[(size_t)row * D + colc] = f2bf(v - bf2f(h));
            }
        }
    }
}

// ---------------------------------------------------------------------------
// Cooperative tail: layer2 (sparse rows) + layer3 (32 roots) + MLP head.
// 128 blocks x 1024 threads, 3 grid syncs, monotonic barrier (R5-proven logic).
// ---------------------------------------------------------------------------
__device__ int g_cnt;   // zero-init at module load; monotonic forever
__device__ int g_gen;

static __device__ __forceinline__ void gridsync() {
    __threadfence();
    __syncthreads();
    if (threadIdx.x == 0) {
        int g = __hip_atomic_load(&g_gen, __ATOMIC_RELAXED, __HIP_MEMORY_SCOPE_AGENT);
        int v = __hip_atomic_fetch_add(&g_cnt, 1, __ATOMIC_RELAXED, __HIP_MEMORY_SCOPE_AGENT);
        if ((v & (TAILB - 1)) == (TAILB - 1))
            __hip_atomic_fetch_add(&g_gen, 1, __ATOMIC_RELAXED, __HIP_MEMORY_SCOPE_AGENT);
        while (__hip_atomic_load(&g_gen, __ATOMIC_RELAXED, __HIP_MEMORY_SCOPE_AGENT) == g)
            __builtin_amdgcn_s_sleep(2);
    }
    __syncthreads();
    __threadfence();
}

struct TailLds {
    union {
        struct {
            __attribute__((aligned(16))) u16 As[2][32 * 40];    // 80B row stride
            __attribute__((aligned(16))) u16 Bs[2][256 * 40];
            int rid[32];
            int aid[32];
        } g;
        struct { float h[D]; float part[4][D]; } hd;
    };
};

__global__ __launch_bounds__(1024, 1) void tail_kernel(
    const int* __restrict__ cnt, const int* __restrict__ col,
    const int* __restrict__ l2list, const int* __restrict__ l2cntp,
    u16* xb1h, u16* xb1l,          // X1 (full, in) / X3 (roots, out)
    u16* xb0h, u16* xb0l,          // X2 out (l2 rows)
    u16* agghi, u16* agglo,        // rows [0,16384) layer aggs + [16384,16416) scratch
    const u16* __restrict__ wtlhi, const u16* __restrict__ wtllo,
    const u16* __restrict__ wtrhi, const u16* __restrict__ wtrlo,
    const float* __restrict__ bl,
    const float* __restrict__ Wh, const float* __restrict__ bh,
    const float* __restrict__ Wo, const float* __restrict__ bo,
    float* __restrict__ out)
{
    __shared__ TailLds L;
    const int bid = blockIdx.x;
    const int t = threadIdx.x;
    const int w = t >> 6, lane = t & 63;
    const int nl2raw = *l2cntp;
    const int nl2 = nl2raw > L2CAP ? L2CAP : nl2raw;

    // dual-GEMM over one 32-row tile x 256 cols; rows from L.g.rid (X) / L.g.aid (agg)
    auto gemm_tile = [&](const u16* Xh, const u16* Xl,
                         const u16* Ah, const u16* Al,
                         const u16* WRh, const u16* WRl,
                         const u16* WLh, const u16* WLl,
                         const float* bias, u16* Oh, u16* Ol) {
        f32x16 acc;
        #pragma unroll
        for (int j = 0; j < 16; ++j) acc[j] = 0.f;
        for (int ph = 0; ph < 2; ++ph) {
            const u16* ah = ph ? Ah : Xh;
            const u16* al = ph ? Al : Xl;
            const u16* bh_ = ph ? WLh : WRh;
            const u16* bl_ = ph ? WLl : WRl;
            for (int k0 = 0; k0 < 8; ++k0) {
                __syncthreads();
                {   // stage A 32x32 hi+lo (1 elem/thread each)
                    int row = t >> 5, kk = t & 31;
                    int rg = ph ? L.g.aid[row] : L.g.rid[row];
                    L.g.As[0][row * 40 + kk] = ah[(size_t)rg * D + k0 * 32 + kk];
                    L.g.As[1][row * 40 + kk] = al[(size_t)rg * D + k0 * 32 + kk];
                }
                {   // stage B 256x32 hi+lo (u16x8/thread each)
                    int n = t >> 2, kq = t & 3;
                    *(u16x8*)&L.g.Bs[0][n * 40 + kq * 8] =
                        *(const u16x8*)&bh_[(size_t)n * D + k0 * 32 + kq * 8];
                    *(u16x8*)&L.g.Bs[1][n * 40 + kq * 8] =
                        *(const u16x8*)&bl_[(size_t)n * D + k0 * 32 + kq * 8];
                }
                __syncthreads();
                if (w < 8) {
                    #pragma unroll
                    for (int s = 0; s < 2; ++s) {
                        int kb = s * 32 + (lane >> 5) * 16;
                        bf16x8 fah = *(const bf16x8*)((char*)&L.g.As[0][0] + (lane & 31) * 80 + kb);
                        bf16x8 fal = *(const bf16x8*)((char*)&L.g.As[1][0] + (lane & 31) * 80 + kb);
                        int n = w * 32 + (lane & 31);
                        bf16x8 fbh = *(const bf16x8*)((char*)&L.g.Bs[0][0] + n * 80 + kb);
                        bf16x8 fbl = *(const bf16x8*)((char*)&L.g.Bs[1][0] + n * 80 + kb);
                        acc = __builtin_amdgcn_mfma_f32_32x32x16_bf16(fah, fbh, acc, 0, 0, 0);
                        acc = __builtin_amdgcn_mfma_f32_32x32x16_bf16(fal, fbh, acc, 0, 0, 0);
                        acc = __builtin_amdgcn_mfma_f32_32x32x16_bf16(fah, fbl, acc, 0, 0, 0);
                    }
                }
            }
        }
        __syncthreads();
        if (w < 8) {
            int colc = w * 32 + (lane & 31);
            float bv = bias[colc];
            #pragma unroll
            for (int reg = 0; reg < 16; ++reg) {
                int row = (reg & 3) + 8 * (reg >> 2) + 4 * (lane >> 5);
                int rg = L.g.rid[row];
                float v = acc[reg] + bv;
                u16 h = f2bf(v);
                Oh[(size_t)rg * D + colc] = h;
                Ol[(size_t)rg * D + colc] = f2bf(v - bf2f(h));
            }
        }
    };

    // ---- T1: layer-2 aggregation over l2-active nodes ----
    for (int n = bid * 16 + w; n < nl2; n += TAILB * 16) {
        int node = l2list[n];
        agg_node(xb1h, cnt, col, node, node, lane, agghi, agglo);
    }
    gridsync();

    // ---- T2: layer-2 dual GEMM on l2 rows ----
    if (bid * 32 < nl2) {
        if (t < 32) {
            int idx = bid * 32 + t;
            if (idx > nl2 - 1) idx = nl2 - 1;      // clamp-pad: duplicate rows, same values
            int r = l2list[idx];
            L.g.rid[t] = r;
            L.g.aid[t] = r;
        }
        gemm_tile(xb1h, xb1l, agghi, agglo,
                  wtrhi + 65536, wtrlo + 65536, wtlhi + 65536, wtllo + 65536,
                  bl + D, xb0h, xb0l);
    }
    gridsync();

    // ---- T3: layer-3 for the 32 roots (block 0 only) ----
    if (bid == 0) {
        for (int i = w; i < B_GRAPHS; i += 16)
            agg_node(xb0h, cnt, col, i * NODES_PER_GRAPH, N_NODES + i, lane, agghi, agglo);
        asm volatile("s_waitcnt vmcnt(0)" ::: "memory");   // drain agg writes to L2
        __syncthreads();
        if (t < 32) {
            L.g.rid[t] = t * NODES_PER_GRAPH;              // output/X rows: roots
            L.g.aid[t] = N_NODES + t;                      // agg rows: fresh scratch (no stale L1)
        }
        gemm_tile(xb0h, xb0l, agghi, agglo,
                  wtrhi + 2 * 65536, wtrlo + 2 * 65536, wtlhi + 2 * 65536, wtllo + 2 * 65536,
                  bl + 2 * D, xb1h, xb1l);
    }
    gridsync();

    // ---- T4: MLP head (blocks 0..31, one graph each) ----
    if (bid < B_GRAPHS) {
        if (t < D) {
            size_t idx = (size_t)(bid * NODES_PER_GRAPH) * D + t;
            L.hd.h[t] = bf2f(xb1h[idx]) + bf2f(xb1l[idx]);
        }
        __syncthreads();
        const int c = t & 255, kq = t >> 8;
        for (int l = 0; l < 3; ++l) {
            const float* W = (l < 2) ? Wh + (size_t)l * D * D : Wo;
            float acc = 0.f;
            #pragma unroll
            for (int k0 = 0; k0 < 64; k0 += 8) {
                float wv[8];
                #pragma unroll
                for (int j = 0; j < 8; ++j)
                    wv[j] = W[(size_t)(kq * 64 + k0 + j) * D + c];
                #pragma unroll
                for (int j = 0; j < 8; ++j)
                    acc += L.hd.h[kq * 64 + k0 + j] * wv[j];
            }
            L.hd.part[kq][c] = acc;
            __syncthreads();
            if (t < D) {
                float v = L.hd.part[0][t] + L.hd.part[1][t] + L.hd.part[2][t] + L.hd.part[3][t]
                        + ((l < 2) ? bh[(size_t)l * D + t] : bo[t]);
                if (l < 2) L.hd.h[t] = fmaxf(v, 0.f);
                else       out[(size_t)bid * D + t] = v;
            }
            __syncthreads();
        }
    }
}

// ---------------------------------------------------------------------------
extern "C" void kernel_launch(void* const* d_in, const int* in_sizes, int n_in,
                              void* d_out, int out_size, void* d_ws, size_t ws_size,
                              hipStream_t stream) {
    const float* x    = (const float*)d_in[0];
    const int*   edge = (const int*)d_in[1];
    const float* Wl   = (const float*)d_in[2];
    const float* bl   = (const float*)d_in[3];
    const float* Wr   = (const float*)d_in[4];
    const float* Wh   = (const float*)d_in[5];
    const float* bh   = (const float*)d_in[6];
    const float* Wo   = (const float*)d_in[7];
    const float* bo   = (const float*)d_in[8];
    float* out = (float*)d_out;

    char* w = (char*)d_ws;
    auto alloc = [&](size_t bytes) {
        char* p = w;
        w += (bytes + 255) & ~(size_t)255;
        return p;
    };
    int* cnt    = (int*)alloc((size_t)N_NODES * 4);
    int* col    = (int*)alloc((size_t)N_NODES * MAXDEG * 4);
    int* flags  = (int*)alloc((size_t)N_NODES * 4);
    int* l2list = (int*)alloc((size_t)4096 * 4);
    int* l2cnt  = (int*)alloc(256);
    u16* Xh[2] = {(u16*)alloc((size_t)N_NODES * D * 2), (u16*)alloc((size_t)N_NODES * D * 2)};
    u16* Xl[2] = {(u16*)alloc((size_t)N_NODES * D * 2), (u16*)alloc((size_t)N_NODES * D * 2)};
    u16* Agghi = (u16*)alloc((size_t)(N_NODES + 32) * D * 2);
    u16* Agglo = (u16*)alloc((size_t)(N_NODES + 32) * D * 2);
    u16* WtLhi = (u16*)alloc((size_t)3 * 65536 * 2);
    u16* WtLlo = (u16*)alloc((size_t)3 * 65536 * 2);
    u16* WtRhi = (u16*)alloc((size_t)3 * 65536 * 2);
    u16* WtRlo = (u16*)alloc((size_t)3 * 65536 * 2);

    prep_kernel<<<2273, 256, 0, stream>>>(x, Wl, Wr, Xh[0], Xl[0],
                                          WtLhi, WtLlo, WtRhi, WtRlo,
                                          cnt, flags, l2list, l2cnt);
    fill_bucket_kernel<<<N_EDGES / 256, 256, 0, stream>>>(edge, cnt, col,
                                                          flags, l2list, l2cnt);
    // layer 1 (full graph)
    agg_kernel<<<N_NODES / 4, 256, 0, stream>>>(Xh[0], cnt, col, Agghi, Agglo);
    gemm_mfma_kernel<<<256, 256, 0, stream>>>(
        Xh[0], Xl[0], Agghi, Agglo,
        WtRhi, WtRlo, WtLhi, WtLlo,
        bl, Xh[1], Xl[1]);
    // layers 2+3 + head, cooperative
    tail_kernel<<<TAILB, 1024, 0, stream>>>(
        cnt, col, l2list, l2cnt,
        Xh[1], Xl[1], Xh[0], Xl[0],
        Agghi, Agglo,
        WtLhi, WtLlo, WtRhi, WtRlo,
        bl, Wh, bh, Wo, bo, out);
}

// Round 8
// 128.858 us; speedup vs baseline: 2.5722x; 2.5722x over previous
//
#include <hip/hip_runtime.h>

#define N_NODES 16384
#define N_EDGES 262144
#define D 256
#define B_GRAPHS 32
#define NODES_PER_GRAPH 512   // N_NODES / B_GRAPHS
#define MAXDEG 64             // Poisson(16): P(deg>64) ~ 1e-17
#define L2CAP 2080            // 32 roots + 32*64 max captured srcs

typedef unsigned short u16;
typedef __attribute__((ext_vector_type(8)))  short bf16x8;
typedef __attribute__((ext_vector_type(16))) float f32x16;
typedef __attribute__((ext_vector_type(8)))  unsigned short u16x8;
typedef __attribute__((ext_vector_type(4)))  unsigned short u16x4;

static __device__ __forceinline__ u16 f2bf(float f) {
    unsigned int u = __float_as_uint(f);
    unsigned int r = (u + 0x7FFFu + ((u >> 16) & 1u)) >> 16;   // RNE
    return (u16)r;
}
static __device__ __forceinline__ float bf2f(u16 h) {
    return __uint_as_float(((unsigned int)h) << 16);
}
// involution swizzle on byte offsets within an 8KB [128 rows x 64B] LDS array
static __device__ __forceinline__ int swz(int a) {
    return a ^ (((a >> 7) & 3) << 4);
}
static __device__ __forceinline__ void gload16(const void* g, void* l) {
    __builtin_amdgcn_global_load_lds(
        (const __attribute__((address_space(1))) unsigned int*)g,
        (__attribute__((address_space(3))) unsigned int*)l, 16, 0, 0);
}

// ---------------------------------------------------------------------------
// prep: [0,2048) split x; [2048,2144) W transpose+split; [2144,2208) zero cnt;
//       [2208,2272) init flags (roots pre-set); [2272] seed l2 list
// ---------------------------------------------------------------------------
__global__ __launch_bounds__(256) void prep_kernel(
    const float* __restrict__ x, const float* __restrict__ Wl,
    const float* __restrict__ Wr,
    u16* __restrict__ Xhi, u16* __restrict__ Xlo,
    u16* __restrict__ WtL_hi, u16* __restrict__ WtL_lo,
    u16* __restrict__ WtR_hi, u16* __restrict__ WtR_lo,
    int* __restrict__ cnt, int* __restrict__ flags,
    int* __restrict__ l2list, int* __restrict__ l2cnt)
{
    __shared__ float S[64][68];
    const int bid = blockIdx.x;
    const int t = threadIdx.x;
    if (bid < 2048) {
        size_t e0 = ((size_t)bid * 256 + t) * 8;
        float4 v0 = *(const float4*)&x[e0];
        float4 v1 = *(const float4*)&x[e0 + 4];
        float xs[8] = {v0.x, v0.y, v0.z, v0.w, v1.x, v1.y, v1.z, v1.w};
        u16x8 H, L;
        #pragma unroll
        for (int j = 0; j < 8; ++j) {
            u16 h = f2bf(xs[j]);
            H[j] = h; L[j] = f2bf(xs[j] - bf2f(h));
        }
        *(u16x8*)&Xhi[e0] = H;
        *(u16x8*)&Xlo[e0] = L;
    } else if (bid < 2144) {
        int mb = bid - 2048;
        int mat = mb / 16, sub = mb % 16;
        int kt = (sub >> 2) * 64, nt = (sub & 3) * 64;
        const float* src = (mat < 3) ? Wl + (size_t)mat * 65536 : Wr + (size_t)(mat - 3) * 65536;
        u16* dhi = (mat < 3) ? WtL_hi + (size_t)mat * 65536 : WtR_hi + (size_t)(mat - 3) * 65536;
        u16* dlo = (mat < 3) ? WtL_lo + (size_t)mat * 65536 : WtR_lo + (size_t)(mat - 3) * 65536;
        int r = t >> 2, c0 = (t & 3) * 16;
        #pragma unroll
        for (int j = 0; j < 4; ++j) {
            float4 v = *(const float4*)&src[(size_t)(kt + r) * 256 + nt + c0 + j * 4];
            *(float4*)&S[r][c0 + j * 4] = v;
        }
        __syncthreads();
        int n = t >> 2, kc = (t & 3) * 16;
        u16x8 h0, h1, l0, l1;
        #pragma unroll
        for (int j = 0; j < 8; ++j) {
            float xv = S[kc + j][n];
            u16 h = f2bf(xv);
            h0[j] = h; l0[j] = f2bf(xv - bf2f(h));
            float y = S[kc + 8 + j][n];
            u16 g = f2bf(y);
            h1[j] = g; l1[j] = f2bf(y - bf2f(g));
        }
        size_t o = (size_t)(nt + n) * 256 + kt + kc;
        *(u16x8*)&dhi[o] = h0; *(u16x8*)&dhi[o + 8] = h1;
        *(u16x8*)&dlo[o] = l0; *(u16x8*)&dlo[o + 8] = l1;
    } else if (bid < 2208) {
        cnt[(bid - 2144) * 256 + t] = 0;
    } else if (bid < 2272) {
        int i = (bid - 2208) * 256 + t;
        flags[i] = ((i & (NODES_PER_GRAPH - 1)) == 0) ? 1 : 0;  // roots pre-marked
    } else {
        if (t < B_GRAPHS) l2list[t] = t * NODES_PER_GRAPH;
        if (t == 0) *l2cnt = B_GRAPHS;
    }
}

// ---------------------------------------------------------------------------
// bucket fill + L2-active capture (srcs of edges into roots, deduped)
// ---------------------------------------------------------------------------
__global__ __launch_bounds__(256) void fill_bucket_kernel(const int* __restrict__ edge,
                                                          int* __restrict__ cnt,
                                                          int* __restrict__ col,
                                                          int* __restrict__ flags,
                                                          int* __restrict__ l2list,
                                                          int* __restrict__ l2cnt) {
    int e = blockIdx.x * 256 + threadIdx.x;
    int dst = edge[N_EDGES + e];
    int src = edge[e];
    int slot = atomicAdd(&cnt[dst], 1);
    if (slot < MAXDEG) {
        col[dst * MAXDEG + slot] = src;
        if ((dst & (NODES_PER_GRAPH - 1)) == 0) {     // dst is a root
            if (atomicCAS(&flags[src], 0, 1) == 0) {
                int p = atomicAdd(l2cnt, 1);
                if (p < L2CAP) l2list[p] = src;
            }
        }
    }
}

// ---------------------------------------------------------------------------
// per-node mean-aggregate helper (64-lane wave), gathers HI only, writes hi/lo
// ---------------------------------------------------------------------------
static __device__ __forceinline__ void agg_node(const u16* __restrict__ Xs,
                                                const int* __restrict__ cnt,
                                                const int* __restrict__ col,
                                                int node, int lane,
                                                u16* __restrict__ Ah,
                                                u16* __restrict__ Al) {
    int c = cnt[node];
    if (c > MAXDEG) c = MAXDEG;
    int my = (lane < c) ? col[node * MAXDEG + lane] : 0;
    float a0 = 0.f, a1 = 0.f, a2 = 0.f, a3 = 0.f;
    int j = 0;
    for (; j + 8 <= c; j += 8) {
        u16x4 v[8];
        #pragma unroll
        for (int q = 0; q < 8; ++q) {
            int s = __shfl(my, j + q);
            v[q] = *(const u16x4*)&Xs[(size_t)s * D + lane * 4];
        }
        #pragma unroll
        for (int q = 0; q < 8; ++q) {
            a0 += bf2f(v[q][0]); a1 += bf2f(v[q][1]);
            a2 += bf2f(v[q][2]); a3 += bf2f(v[q][3]);
        }
    }
    for (; j < c; ++j) {
        int s = __shfl(my, j);
        u16x4 v = *(const u16x4*)&Xs[(size_t)s * D + lane * 4];
        a0 += bf2f(v[0]); a1 += bf2f(v[1]); a2 += bf2f(v[2]); a3 += bf2f(v[3]);
    }
    float id = 1.0f / (float)(c < 1 ? 1 : c);
    float m[4] = {a0 * id, a1 * id, a2 * id, a3 * id};
    u16x4 H, L;
    #pragma unroll
    for (int q = 0; q < 4; ++q) {
        u16 h = f2bf(m[q]);
        H[q] = h; L[q] = f2bf(m[q] - bf2f(h));
    }
    *(u16x4*)&Ah[(size_t)node * D + lane * 4] = H;
    *(u16x4*)&Al[(size_t)node * D + lane * 4] = L;
}

// ---------------------------------------------------------------------------
// full-graph aggregation (layer 1)
// ---------------------------------------------------------------------------
__global__ __launch_bounds__(256) void agg_kernel(const u16* __restrict__ Xhi,
                                                  const int* __restrict__ cnt,
                                                  const int* __restrict__ col,
                                                  u16* __restrict__ Agghi,
                                                  u16* __restrict__ Agglo) {
    int node = blockIdx.x * 4 + (threadIdx.x >> 6);
    agg_node(Xhi, cnt, col, node, threadIdx.x & 63, Agghi, Agglo);
}

// ---------------------------------------------------------------------------
// sparse aggregation over listed nodes (layers 2 and 3)
// mode 0: nodes from l2list[0..nl2); mode 1: the 32 roots
// ---------------------------------------------------------------------------
__global__ __launch_bounds__(256) void agg_sparse_kernel(const u16* __restrict__ Xhi,
                                                         const int* __restrict__ cnt,
                                                         const int* __restrict__ col,
                                                         const int* __restrict__ l2list,
                                                         const int* __restrict__ l2cntp,
                                                         int mode,
                                                         u16* __restrict__ Agghi,
                                                         u16* __restrict__ Agglo) {
    int g = blockIdx.x * 4 + (threadIdx.x >> 6);
    int node;
    if (mode == 0) {
        int nl2 = *l2cntp; if (nl2 > L2CAP) nl2 = L2CAP;
        if (g >= nl2) return;
        node = l2list[g];
    } else {
        if (g >= B_GRAPHS) return;
        node = g * NODES_PER_GRAPH;
    }
    agg_node(Xhi, cnt, col, node, threadIdx.x & 63, Agghi, Agglo);
}

// ---------------------------------------------------------------------------
// full MFMA dual GEMM (layer 1) — R4/R6 proven
// ---------------------------------------------------------------------------
__global__ __launch_bounds__(256) void gemm_mfma_kernel(
    const u16* __restrict__ Xhi,   const u16* __restrict__ Xlo,
    const u16* __restrict__ Agghi, const u16* __restrict__ Agglo,
    const u16* __restrict__ WtRhi, const u16* __restrict__ WtRlo,
    const u16* __restrict__ WtLhi, const u16* __restrict__ WtLlo,
    const float* __restrict__ bias,
    u16* __restrict__ Xohi, u16* __restrict__ Xolo)
{
    __shared__ u16 lds[2][4][4096];   // [buf][Ahi,Alo,Bhi,Blo][8KB]

    const int tid  = threadIdx.x;
    const int w    = tid >> 6, lane = tid & 63;
    const int wm   = w >> 1, wn = w & 1;
    const int bid  = blockIdx.x;
    const int m0   = (bid >> 1) * 128;
    const int n0   = (bid & 1) * 128;

    f32x16 acc[4];
    #pragma unroll
    for (int f = 0; f < 4; ++f)
        #pragma unroll
        for (int j = 0; j < 16; ++j) acc[f][j] = 0.f;

    const int r32 = lane & 31;
    const int khb = (lane >> 5) * 16;

    auto stage = [&](int buf, int tt) {
        const u16* src; int rbase;
        const int k0 = (tt & 7) * 32;
        const bool ph2 = tt >= 8;
        if      (w == 0) { src = ph2 ? Agghi : Xhi;  rbase = m0; }
        else if (w == 1) { src = ph2 ? Agglo : Xlo;  rbase = m0; }
        else if (w == 2) { src = ph2 ? WtLhi : WtRhi; rbase = n0; }
        else             { src = ph2 ? WtLlo : WtRlo; rbase = n0; }
        char* base = (char*)&lds[buf][w][0];
        #pragma unroll
        for (int i = 0; i < 8; ++i) {
            int o = i * 1024 + lane * 16;
            int a = swz(o);
            const u16* g = src + (size_t)(rbase + (a >> 6)) * D + k0 + ((a & 63) >> 1);
            gload16(g, base + i * 1024);
        }
    };

    auto compute = [&](int buf) {
        const char* Ah = (const char*)&lds[buf][0][0];
        const char* Al = (const char*)&lds[buf][1][0];
        const char* Bh = (const char*)&lds[buf][2][0];
        const char* Bl = (const char*)&lds[buf][3][0];
        #pragma unroll
        for (int s = 0; s < 2; ++s) {
            const int cb = s * 32 + khb;
            const int ra0 = wm * 64 + r32, ra1 = ra0 + 32;
            const int rb0 = wn * 64 + r32, rb1 = rb0 + 32;
            bf16x8 ah0 = *(const bf16x8*)(Ah + swz(ra0 * 64 + cb));
            bf16x8 ah1 = *(const bf16x8*)(Ah + swz(ra1 * 64 + cb));
            bf16x8 al0 = *(const bf16x8*)(Al + swz(ra0 * 64 + cb));
            bf16x8 al1 = *(const bf16x8*)(Al + swz(ra1 * 64 + cb));
            bf16x8 bh0 = *(const bf16x8*)(Bh + swz(rb0 * 64 + cb));
            bf16x8 bh1 = *(const bf16x8*)(Bh + swz(rb1 * 64 + cb));
            bf16x8 bl0 = *(const bf16x8*)(Bl + swz(rb0 * 64 + cb));
            bf16x8 bl1 = *(const bf16x8*)(Bl + swz(rb1 * 64 + cb));
            acc[0] = __builtin_amdgcn_mfma_f32_32x32x16_bf16(ah0, bh0, acc[0], 0, 0, 0);
            acc[1] = __builtin_amdgcn_mfma_f32_32x32x16_bf16(ah0, bh1, acc[1], 0, 0, 0);
            acc[2] = __builtin_amdgcn_mfma_f32_32x32x16_bf16(ah1, bh0, acc[2], 0, 0, 0);
            acc[3] = __builtin_amdgcn_mfma_f32_32x32x16_bf16(ah1, bh1, acc[3], 0, 0, 0);
            acc[0] = __builtin_amdgcn_mfma_f32_32x32x16_bf16(al0, bh0, acc[0], 0, 0, 0);
            acc[1] = __builtin_amdgcn_mfma_f32_32x32x16_bf16(al0, bh1, acc[1], 0, 0, 0);
            acc[2] = __builtin_amdgcn_mfma_f32_32x32x16_bf16(al1, bh0, acc[2], 0, 0, 0);
            acc[3] = __builtin_amdgcn_mfma_f32_32x32x16_bf16(al1, bh1, acc[3], 0, 0, 0);
            acc[0] = __builtin_amdgcn_mfma_f32_32x32x16_bf16(ah0, bl0, acc[0], 0, 0, 0);
            acc[1] = __builtin_amdgcn_mfma_f32_32x32x16_bf16(ah0, bl1, acc[1], 0, 0, 0);
            acc[2] = __builtin_amdgcn_mfma_f32_32x32x16_bf16(ah1, bl0, acc[2], 0, 0, 0);
            acc[3] = __builtin_amdgcn_mfma_f32_32x32x16_bf16(ah1, bl1, acc[3], 0, 0, 0);
        }
    };

    stage(0, 0);
    __syncthreads();
    int cur = 0;
    for (int t = 0; t < 16; ++t) {
        if (t < 15) stage(cur ^ 1, t + 1);
        compute(cur);
        __syncthreads();
        cur ^= 1;
    }

    #pragma unroll
    for (int fm = 0; fm < 2; ++fm) {
        #pragma unroll
        for (int fn = 0; fn < 2; ++fn) {
            const int colc = n0 + wn * 64 + fn * 32 + r32;
            const int rowb = m0 + wm * 64 + fm * 32 + 4 * (lane >> 5);
            const float bv = bias[colc];
            #pragma unroll
            for (int reg = 0; reg < 16; ++reg) {
                const int row = rowb + (reg & 3) + 8 * (reg >> 2);
                float v = acc[fm * 2 + fn][reg] + bv;
                u16 h = f2bf(v);
                Xohi[(size_t)row * D + colc] = h;
                Xolo[(size_t)row * D + colc] = f2bf(v - bf2f(h));
            }
        }
    }
}

// ---------------------------------------------------------------------------
// sparse dual GEMM: one 32-row tile per block, rows from list (mode 0) or
// roots (mode 1). 1024 threads; waves 0-7 compute one 32x32 frag each.
// Numerics identical to R7's gemm_tile (proven).
// ---------------------------------------------------------------------------
__global__ __launch_bounds__(1024) void gemm_sparse_kernel(
    const int* __restrict__ l2list, const int* __restrict__ l2cntp, int mode,
    const u16* __restrict__ Xh, const u16* __restrict__ Xl,
    const u16* __restrict__ Ah, const u16* __restrict__ Al,
    const u16* __restrict__ WRh, const u16* __restrict__ WRl,
    const u16* __restrict__ WLh, const u16* __restrict__ WLl,
    const float* __restrict__ bias,
    u16* __restrict__ Oh, u16* __restrict__ Ol)
{
    __shared__ __attribute__((aligned(16))) u16 As[2][32 * 40];   // 80B stride
    __shared__ __attribute__((aligned(16))) u16 Bs[2][256 * 40];
    __shared__ int rid[32];

    const int bid = blockIdx.x;
    const int t = threadIdx.x;
    const int w = t >> 6, lane = t & 63;

    if (mode == 0) {
        int nl2 = *l2cntp; if (nl2 > L2CAP) nl2 = L2CAP;
        if (bid * 32 >= nl2) return;
        if (t < 32) {
            int idx = bid * 32 + t;
            if (idx > nl2 - 1) idx = nl2 - 1;   // clamp-pad: duplicate rows, same values
            rid[t] = l2list[idx];
        }
    } else {
        if (t < 32) rid[t] = t * NODES_PER_GRAPH;
    }

    f32x16 acc;
    #pragma unroll
    for (int j = 0; j < 16; ++j) acc[j] = 0.f;

    for (int ph = 0; ph < 2; ++ph) {
        const u16* ah = ph ? Ah : Xh;
        const u16* al = ph ? Al : Xl;
        const u16* bh_ = ph ? WLh : WRh;
        const u16* bl_ = ph ? WLl : WRl;
        for (int k0 = 0; k0 < 8; ++k0) {
            __syncthreads();
            {   // stage A 32x32 hi+lo
                int row = t >> 5, kk = t & 31;
                int rg = rid[row];
                As[0][row * 40 + kk] = ah[(size_t)rg * D + k0 * 32 + kk];
                As[1][row * 40 + kk] = al[(size_t)rg * D + k0 * 32 + kk];
            }
            {   // stage B 256x32 hi+lo
                int n = t >> 2, kq = t & 3;
                *(u16x8*)&Bs[0][n * 40 + kq * 8] =
                    *(const u16x8*)&bh_[(size_t)n * D + k0 * 32 + kq * 8];
                *(u16x8*)&Bs[1][n * 40 + kq * 8] =
                    *(const u16x8*)&bl_[(size_t)n * D + k0 * 32 + kq * 8];
            }
            __syncthreads();
            if (w < 8) {
                #pragma unroll
                for (int s = 0; s < 2; ++s) {
                    int kb = s * 32 + (lane >> 5) * 16;
                    bf16x8 fah = *(const bf16x8*)((char*)&As[0][0] + (lane & 31) * 80 + kb);
                    bf16x8 fal = *(const bf16x8*)((char*)&As[1][0] + (lane & 31) * 80 + kb);
                    int n = w * 32 + (lane & 31);
                    bf16x8 fbh = *(const bf16x8*)((char*)&Bs[0][0] + n * 80 + kb);
                    bf16x8 fbl = *(const bf16x8*)((char*)&Bs[1][0] + n * 80 + kb);
                    acc = __builtin_amdgcn_mfma_f32_32x32x16_bf16(fah, fbh, acc, 0, 0, 0);
                    acc = __builtin_amdgcn_mfma_f32_32x32x16_bf16(fal, fbh, acc, 0, 0, 0);
                    acc = __builtin_amdgcn_mfma_f32_32x32x16_bf16(fah, fbl, acc, 0, 0, 0);
                }
            }
        }
    }
    __syncthreads();
    if (w < 8) {
        int colc = w * 32 + (lane & 31);
        float bv = bias[colc];
        #pragma unroll
        for (int reg = 0; reg < 16; ++reg) {
            int row = (reg & 3) + 8 * (reg >> 2) + 4 * (lane >> 5);
            int rg = rid[row];
            float v = acc[reg] + bv;
            u16 h = f2bf(v);
            Oh[(size_t)rg * D + colc] = h;
            Ol[(size_t)rg * D + colc] = f2bf(v - bf2f(h));
        }
    }
}

// ---------------------------------------------------------------------------
// MLP head: 32 blocks x 1024 threads (R4 proven)
// ---------------------------------------------------------------------------
__global__ __launch_bounds__(1024) void head_kernel(const u16* __restrict__ Xhi,
                                                    const u16* __restrict__ Xlo,
                                                    const float* __restrict__ Wh,
                                                    const float* __restrict__ bh,
                                                    const float* __restrict__ Wo,
                                                    const float* __restrict__ bo,
                                                    float* __restrict__ out) {
    __shared__ float h[D];
    __shared__ float part[4][D];
    const int b = blockIdx.x, t = threadIdx.x;
    if (t < D) {
        size_t idx = (size_t)(b * NODES_PER_GRAPH) * D + t;
        h[t] = bf2f(Xhi[idx]) + bf2f(Xlo[idx]);
    }
    __syncthreads();
    const int c = t & 255, kq = t >> 8;
    for (int l = 0; l < 3; ++l) {
        const float* W = (l < 2) ? Wh + (size_t)l * D * D : Wo;
        float acc = 0.f;
        #pragma unroll
        for (int k0 = 0; k0 < 64; k0 += 8) {
            float wv[8];
            #pragma unroll
            for (int j = 0; j < 8; ++j)
                wv[j] = W[(size_t)(kq * 64 + k0 + j) * D + c];
            #pragma unroll
            for (int j = 0; j < 8; ++j)
                acc += h[kq * 64 + k0 + j] * wv[j];
        }
        part[kq][c] = acc;
        __syncthreads();
        if (t < D) {
            float v = part[0][t] + part[1][t] + part[2][t] + part[3][t]
                    + ((l < 2) ? bh[(size_t)l * D + t] : bo[t]);
            if (l < 2) h[t] = fmaxf(v, 0.f);
            else       out[(size_t)b * D + t] = v;
        }
        __syncthreads();
    }
}

// ---------------------------------------------------------------------------
extern "C" void kernel_launch(void* const* d_in, const int* in_sizes, int n_in,
                              void* d_out, int out_size, void* d_ws, size_t ws_size,
                              hipStream_t stream) {
    const float* x    = (const float*)d_in[0];
    const int*   edge = (const int*)d_in[1];
    const float* Wl   = (const float*)d_in[2];
    const float* bl   = (const float*)d_in[3];
    const float* Wr   = (const float*)d_in[4];
    const float* Wh   = (const float*)d_in[5];
    const float* bh   = (const float*)d_in[6];
    const float* Wo   = (const float*)d_in[7];
    const float* bo   = (const float*)d_in[8];
    float* out = (float*)d_out;

    char* w = (char*)d_ws;
    auto alloc = [&](size_t bytes) {
        char* p = w;
        w += (bytes + 255) & ~(size_t)255;
        return p;
    };
    int* cnt    = (int*)alloc((size_t)N_NODES * 4);
    int* col    = (int*)alloc((size_t)N_NODES * MAXDEG * 4);
    int* flags  = (int*)alloc((size_t)N_NODES * 4);
    int* l2list = (int*)alloc((size_t)4096 * 4);
    int* l2cnt  = (int*)alloc(256);
    u16* Xh[2] = {(u16*)alloc((size_t)N_NODES * D * 2), (u16*)alloc((size_t)N_NODES * D * 2)};
    u16* Xl[2] = {(u16*)alloc((size_t)N_NODES * D * 2), (u16*)alloc((size_t)N_NODES * D * 2)};
    u16* Agghi = (u16*)alloc((size_t)N_NODES * D * 2);
    u16* Agglo = (u16*)alloc((size_t)N_NODES * D * 2);
    u16* WtLhi = (u16*)alloc((size_t)3 * 65536 * 2);
    u16* WtLlo = (u16*)alloc((size_t)3 * 65536 * 2);
    u16* WtRhi = (u16*)alloc((size_t)3 * 65536 * 2);
    u16* WtRlo = (u16*)alloc((size_t)3 * 65536 * 2);

    prep_kernel<<<2273, 256, 0, stream>>>(x, Wl, Wr, Xh[0], Xl[0],
                                          WtLhi, WtLlo, WtRhi, WtRlo,
                                          cnt, flags, l2list, l2cnt);
    fill_bucket_kernel<<<N_EDGES / 256, 256, 0, stream>>>(edge, cnt, col,
                                                          flags, l2list, l2cnt);
    // ---- layer 1: full graph ----
    agg_kernel<<<N_NODES / 4, 256, 0, stream>>>(Xh[0], cnt, col, Agghi, Agglo);
    gemm_mfma_kernel<<<256, 256, 0, stream>>>(
        Xh[0], Xl[0], Agghi, Agglo,
        WtRhi, WtRlo, WtLhi, WtLlo,
        bl, Xh[1], Xl[1]);
    // ---- layer 2: only captured rows (roots + their in-neighbors) ----
    agg_sparse_kernel<<<L2CAP / 4, 256, 0, stream>>>(Xh[1], cnt, col,
                                                     l2list, l2cnt, 0, Agghi, Agglo);
    gemm_sparse_kernel<<<L2CAP / 32, 1024, 0, stream>>>(
        l2list, l2cnt, 0,
        Xh[1], Xl[1], Agghi, Agglo,
        WtRhi + 65536, WtRlo + 65536, WtLhi + 65536, WtLlo + 65536,
        bl + D, Xh[0], Xl[0]);
    // ---- layer 3: 32 roots only ----
    agg_sparse_kernel<<<8, 256, 0, stream>>>(Xh[0], cnt, col,
                                             l2list, l2cnt, 1, Agghi, Agglo);
    gemm_sparse_kernel<<<1, 1024, 0, stream>>>(
        l2list, l2cnt, 1,
        Xh[0], Xl[0], Agghi, Agglo,
        WtRhi + 2 * 65536, WtRlo + 2 * 65536, WtLhi + 2 * 65536, WtLlo + 2 * 65536,
        bl + 2 * D, Xh[1], Xl[1]);
    // ---- head ----
    head_kernel<<<B_GRAPHS, 1024, 0, stream>>>(Xh[1], Xl[1], Wh, bh, Wo, bo, out);
}